// Round 2
// baseline (1099.312 us; speedup 1.0000x reference)
//
#include <hip/hip_runtime.h>

#define H 512
#define OW 128
#define NB 16384
#define BM 128
#define BK 64

typedef float f32x4 __attribute__((ext_vector_type(4)));
typedef short short8 __attribute__((ext_vector_type(8)));
typedef unsigned short ushort8v __attribute__((ext_vector_type(8)));

static __device__ __forceinline__ unsigned short f2bf(float f) {
    union { float f; unsigned u; } v; v.f = f;
    return (unsigned short)((v.u + 0x7FFFu + ((v.u >> 16) & 1u)) >> 16);  // RNE
}

static __device__ __forceinline__ f32x4 mfma16(short8 a, short8 b, f32x4 c) {
    return __builtin_amdgcn_mfma_f32_16x16x32_bf16(a, b, c, 0, 0, 0);
}

// async global->LDS, 16B per lane. lds layout: [row][64 shorts], 16B chunk c of
// row r holds logical chunk (c ^ (r&7))  -> conflict-free b128 frag reads.
static __device__ __forceinline__ void stage_tile(
    const unsigned short* __restrict__ g, int gstride /*shorts*/,
    unsigned short* l, int wave, int lane) {
    const int sub = lane >> 3;                 // row within 8-row group
    const int ch  = (lane & 7) ^ sub;          // swizzled source chunk
#pragma unroll
    for (int it = 0; it < 4; ++it) {
        const int row0 = it * 32 + wave * 8;
        const unsigned short* gp = g + (size_t)(row0 + sub) * gstride + ch * 8;
        unsigned short* lp = l + row0 * 64;
        __builtin_amdgcn_global_load_lds(
            (const __attribute__((address_space(1))) void*)gp,
            (__attribute__((address_space(3))) void*)lp, 16, 0, 0);
    }
}

// swizzled b128 fragment read: logical (row, 16B-chunk ch)
static __device__ __forceinline__ short8 frag(const unsigned short* l, int row, int ch) {
    return *(const short8*)&l[row * 64 + ((ch ^ (row & 7)) << 3)];
}

// ---- prep: weights transpose+cast, x cast ----
__global__ void prep_w1(const float* __restrict__ share_W1,
                        const float* __restrict__ task_W1,
                        unsigned short* __restrict__ w1t) {
    const int inst = blockIdx.z;
    const float* src = (inst < 5) ? (share_W1 + (size_t)inst * H * H)
                                  : (task_W1 + (size_t)(inst - 5) * H * H);
    unsigned short* dst = w1t + (size_t)inst * H * H;
    const int g = blockIdx.x * 256 + threadIdx.x;
    const int n = g & (H - 1);
    const int kc = g >> 9;
    float v[8];
#pragma unroll
    for (int i = 0; i < 8; ++i) v[i] = src[(size_t)(kc * 8 + i) * H + n];
    ushort8v o;
#pragma unroll
    for (int i = 0; i < 8; ++i) o[i] = f2bf(v[i]);
    *(ushort8v*)&dst[(size_t)n * H + kc * 8] = o;
}

__global__ void prep_w2(const float* __restrict__ share_W2,
                        const float* __restrict__ task_W2,
                        unsigned short* __restrict__ w2t) {
    const int inst = blockIdx.z;
    const float* src = (inst < 5) ? (share_W2 + (size_t)inst * H * OW)
                                  : (task_W2 + (size_t)(inst - 5) * H * OW);
    unsigned short* dst = w2t + (size_t)inst * OW * H;
    const int g = blockIdx.x * 256 + threadIdx.x;
    const int n = g & (OW - 1);
    const int kc = g >> 7;
    float v[8];
#pragma unroll
    for (int i = 0; i < 8; ++i) v[i] = src[(size_t)(kc * 8 + i) * OW + n];
    ushort8v o;
#pragma unroll
    for (int i = 0; i < 8; ++i) o[i] = f2bf(v[i]);
    *(ushort8v*)&dst[(size_t)n * H + kc * 8] = o;
}

__global__ void prep_x(const float* __restrict__ x0, const float* __restrict__ x1,
                       const float* __restrict__ x2, unsigned short* __restrict__ xb) {
    const int z = blockIdx.z;
    const float* s = (z == 0) ? x0 : (z == 1 ? x1 : x2);
    const size_t g = (size_t)(blockIdx.x * 256 + threadIdx.x) * 8;
    float4 a = *(const float4*)&s[g];
    float4 b = *(const float4*)&s[g + 4];
    ushort8v o;
    o[0] = f2bf(a.x); o[1] = f2bf(a.y); o[2] = f2bf(a.z); o[3] = f2bf(a.w);
    o[4] = f2bf(b.x); o[5] = f2bf(b.y); o[6] = f2bf(b.z); o[7] = f2bf(b.w);
    *(ushort8v*)&xb[(size_t)z * NB * H + g] = o;
}

// ---- fused expert kernel ----
// 256 thr = 4 waves (2x2), wave tile 64x64 of 128x128. LDS 32KB -> 3 blocks/CU.
__global__ __launch_bounds__(256, 3) void expert_fused(
    const unsigned short* __restrict__ xb,
    const float* __restrict__ share_b1, const float* __restrict__ task_b1,
    const float* __restrict__ share_b2, const float* __restrict__ task_b2,
    const unsigned short* __restrict__ w1t, const unsigned short* __restrict__ w2t,
    float* __restrict__ out)
{
    __shared__ unsigned short smem[16384];     // 32 KB
    unsigned short* sA  = smem;                // [128][64] x tile      (GEMM1)
    unsigned short* sBt = smem + 8192;         // [128][64] W1t tile    (GEMM1)
    unsigned short* sH  = smem;                // [128][64] h half      (GEMM2, alias)
    unsigned short* sW2 = smem + 8192;         // [128][64] W2t slice   (GEMM2, alias)

    const int tid  = threadIdx.x;
    const int lane = tid & 63;
    const int wave = __builtin_amdgcn_readfirstlane(tid >> 6);
    const int wy = wave >> 1, wx = wave & 1;
    const int lm = lane & 15;
    const int lq = lane >> 4;

    const int rowtile = blockIdx.x;   // 0..127
    const int e = blockIdx.y;         // 0..4
    const int z = blockIdx.z;         // 0..2
    const int inst = z * 5 + e;

    const float* b1 = (z == 0) ? (share_b1 + e * H)  : (task_b1 + ((z - 1) * 5 + e) * H);
    const float* b2 = (z == 0) ? (share_b2 + e * OW) : (task_b2 + ((z - 1) * 5 + e) * OW);
    const unsigned short* W1 = w1t + (size_t)inst * H * H;    // [n=512][k=512]
    const unsigned short* W2 = w2t + (size_t)inst * OW * H;   // [n=128][k=512]
    const unsigned short* xrow = xb + (size_t)z * NB * H + (size_t)rowtile * BM * H;
    float* op = out + (size_t)inst * NB * OW + (size_t)rowtile * BM * OW;

    const f32x4 z4 = {0.f, 0.f, 0.f, 0.f};
    f32x4 acc_o[4][4];
#pragma unroll
    for (int i = 0; i < 4; ++i)
#pragma unroll
        for (int j = 0; j < 4; ++j) acc_o[i][j] = z4;

    for (int no = 0; no < 4; ++no) {            // h-column chunk = no*128
        f32x4 acc_h[4][4];
#pragma unroll
        for (int i = 0; i < 4; ++i)
#pragma unroll
            for (int j = 0; j < 4; ++j) acc_h[i][j] = z4;

        for (int kt = 0; kt < 8; ++kt) {        // K tiles of 64
            const int k0 = kt * BK;
            stage_tile(xrow + k0, H, sA, wave, lane);
            stage_tile(W1 + (size_t)(no * 128) * H + k0, H, sBt, wave, lane);
            __syncthreads();
#pragma unroll
            for (int kk = 0; kk < 2; ++kk) {
                short8 af[4], bfr[4];
#pragma unroll
                for (int i = 0; i < 4; ++i)
                    af[i] = frag(sA, wy * 64 + i * 16 + lm, kk * 4 + lq);
#pragma unroll
                for (int j = 0; j < 4; ++j)
                    bfr[j] = frag(sBt, wx * 64 + j * 16 + lm, kk * 4 + lq);
#pragma unroll
                for (int i = 0; i < 4; ++i)
#pragma unroll
                    for (int j = 0; j < 4; ++j)
                        acc_h[i][j] = mfma16(af[i], bfr[j], acc_h[i][j]);
            }
            __syncthreads();
        }

        // GEMM2 over this chunk's 128 h-cols, in two K=64 halves
#pragma unroll
        for (int ho = 0; ho < 2; ++ho) {
            if (wx == ho) {
                // write my acc_h cols (local 0..63) as relu(h+b1) bf16 into sH
#pragma unroll
                for (int j = 0; j < 4; ++j) {
                    const int cl = j * 16 + lm;              // local col 0..63
                    const float b1v = b1[no * 128 + ho * 64 + cl];
#pragma unroll
                    for (int i = 0; i < 4; ++i)
#pragma unroll
                        for (int r = 0; r < 4; ++r) {
                            const int row = wy * 64 + i * 16 + lq * 4 + r;
                            float v = fmaxf(acc_h[i][j][r] + b1v, 0.f);
                            sH[row * 64 + (((cl >> 3) ^ (row & 7)) << 3) + (cl & 7)] = f2bf(v);
                        }
                }
            }
            stage_tile(W2 + no * 128 + ho * 64, H, sW2, wave, lane);
            __syncthreads();
#pragma unroll
            for (int kk = 0; kk < 2; ++kk) {
                short8 af[4], bfr[4];
#pragma unroll
                for (int i = 0; i < 4; ++i)
                    af[i] = frag(sH, wy * 64 + i * 16 + lm, kk * 4 + lq);
#pragma unroll
                for (int j = 0; j < 4; ++j)
                    bfr[j] = frag(sW2, wx * 64 + j * 16 + lm, kk * 4 + lq);
#pragma unroll
                for (int i = 0; i < 4; ++i)
#pragma unroll
                    for (int j = 0; j < 4; ++j)
                        acc_o[i][j] = mfma16(af[i], bfr[j], acc_o[i][j]);
            }
            __syncthreads();
        }
    }

    // epilogue: + b2, store fp32
#pragma unroll
    for (int j = 0; j < 4; ++j) {
        const int col = wx * 64 + j * 16 + lm;
        const float b2v = b2[col];
#pragma unroll
        for (int i = 0; i < 4; ++i)
#pragma unroll
            for (int r = 0; r < 4; ++r) {
                const int row = wy * 64 + i * 16 + lq * 4 + r;
                op[(size_t)row * OW + col] = acc_o[i][j][r] + b2v;
            }
    }
}

extern "C" void kernel_launch(void* const* d_in, const int* in_sizes, int n_in,
                              void* d_out, int out_size, void* d_ws, size_t ws_size,
                              hipStream_t stream) {
    const float* share_x  = (const float*)d_in[0];
    const float* task_x0  = (const float*)d_in[1];
    const float* task_x1  = (const float*)d_in[2];
    const float* share_W1 = (const float*)d_in[3];
    const float* share_b1 = (const float*)d_in[4];
    const float* share_W2 = (const float*)d_in[5];
    const float* share_b2 = (const float*)d_in[6];
    const float* task_W1  = (const float*)d_in[7];
    const float* task_b1  = (const float*)d_in[8];
    const float* task_W2  = (const float*)d_in[9];
    const float* task_b2  = (const float*)d_in[10];
    float* out = (float*)d_out;

    unsigned short* w1t = (unsigned short*)d_ws;                  // 15*512*512
    unsigned short* w2t = w1t + (size_t)15 * H * H;               // 15*128*512
    unsigned short* xb  = w2t + (size_t)15 * OW * H;              // 3*16384*512

    prep_w1<<<dim3(128, 1, 15), 256, 0, stream>>>(share_W1, task_W1, w1t);
    prep_w2<<<dim3(32, 1, 15), 256, 0, stream>>>(share_W2, task_W2, w2t);
    prep_x <<<dim3(4096, 1, 3), 256, 0, stream>>>(share_x, task_x0, task_x1, xb);
    expert_fused<<<dim3(128, 5, 3), 256, 0, stream>>>(
        xb, share_b1, task_b1, share_b2, task_b2, w1t, w2t, out);
}

// Round 3
// 449.521 us; speedup vs baseline: 2.4455x; 2.4455x over previous
//
#include <hip/hip_runtime.h>

#define H 512
#define OW 128
#define NB 16384

typedef float f32x4 __attribute__((ext_vector_type(4)));
typedef short short8 __attribute__((ext_vector_type(8)));
typedef unsigned short ushort8v __attribute__((ext_vector_type(8)));

static __device__ __forceinline__ unsigned short f2bf(float f) {
    union { float f; unsigned u; } v; v.f = f;
    return (unsigned short)((v.u + 0x7FFFu + ((v.u >> 16) & 1u)) >> 16);  // RNE
}

static __device__ __forceinline__ f32x4 mfma16(short8 a, short8 b, f32x4 c) {
    return __builtin_amdgcn_mfma_f32_16x16x32_bf16(a, b, c, 0, 0, 0);
}

// Swizzled LDS tile [rows][64 shorts]: 16B chunk ch of row r lives at phys
// chunk ch^(r&7). Verified conflict-free (round 2: SQ_LDS_BANK_CONFLICT = 0).
static __device__ __forceinline__ void sw_write(unsigned short* l, int row, int ch, ushort8v v) {
    *(ushort8v*)&l[row * 64 + ((ch ^ (row & 7)) << 3)] = v;
}
static __device__ __forceinline__ short8 sw_read(const unsigned short* l, int row, int ch) {
    return *(const short8*)&l[row * 64 + ((ch ^ (row & 7)) << 3)];
}

// ---- prep: weights transpose+cast, x cast (unchanged, proven) ----
__global__ void prep_w1(const float* __restrict__ share_W1,
                        const float* __restrict__ task_W1,
                        unsigned short* __restrict__ w1t) {
    const int inst = blockIdx.z;
    const float* src = (inst < 5) ? (share_W1 + (size_t)inst * H * H)
                                  : (task_W1 + (size_t)(inst - 5) * H * H);
    unsigned short* dst = w1t + (size_t)inst * H * H;
    const int g = blockIdx.x * 256 + threadIdx.x;
    const int n = g & (H - 1);
    const int kc = g >> 9;
    float v[8];
#pragma unroll
    for (int i = 0; i < 8; ++i) v[i] = src[(size_t)(kc * 8 + i) * H + n];
    ushort8v o;
#pragma unroll
    for (int i = 0; i < 8; ++i) o[i] = f2bf(v[i]);
    *(ushort8v*)&dst[(size_t)n * H + kc * 8] = o;
}

__global__ void prep_w2(const float* __restrict__ share_W2,
                        const float* __restrict__ task_W2,
                        unsigned short* __restrict__ w2t) {
    const int inst = blockIdx.z;
    const float* src = (inst < 5) ? (share_W2 + (size_t)inst * H * OW)
                                  : (task_W2 + (size_t)(inst - 5) * H * OW);
    unsigned short* dst = w2t + (size_t)inst * OW * H;
    const int g = blockIdx.x * 256 + threadIdx.x;
    const int n = g & (OW - 1);
    const int kc = g >> 7;
    float v[8];
#pragma unroll
    for (int i = 0; i < 8; ++i) v[i] = src[(size_t)(kc * 8 + i) * OW + n];
    ushort8v o;
#pragma unroll
    for (int i = 0; i < 8; ++i) o[i] = f2bf(v[i]);
    *(ushort8v*)&dst[(size_t)n * H + kc * 8] = o;
}

__global__ void prep_x(const float* __restrict__ x0, const float* __restrict__ x1,
                       const float* __restrict__ x2, unsigned short* __restrict__ xb) {
    const int z = blockIdx.z;
    const float* s = (z == 0) ? x0 : (z == 1 ? x1 : x2);
    const size_t g = (size_t)(blockIdx.x * 256 + threadIdx.x) * 8;
    float4 a = *(const float4*)&s[g];
    float4 b = *(const float4*)&s[g + 4];
    ushort8v o;
    o[0] = f2bf(a.x); o[1] = f2bf(a.y); o[2] = f2bf(a.z); o[3] = f2bf(a.w);
    o[4] = f2bf(b.x); o[5] = f2bf(b.y); o[6] = f2bf(b.z); o[7] = f2bf(b.w);
    *(ushort8v*)&xb[(size_t)z * NB * H + g] = o;
}

// ---- GEMM1: h = relu(x @ W1 + b1), bf16 out to hbuf [5][NB][512] ----
// grid 2560: bid = e + 5*(nt + 4*rowtile). 128x128 tile, K=512.
__global__ __launch_bounds__(256, 3) void gemm1(
    const unsigned short* __restrict__ xb, const unsigned short* __restrict__ w1t,
    const float* __restrict__ share_b1, const float* __restrict__ task_b1,
    unsigned short* __restrict__ hbuf, int z)
{
    __shared__ unsigned short smem[128 * 136];   // staging 2x8192; repack 128x136
    unsigned short* sA  = smem;                  // [128][64]
    unsigned short* sBt = smem + 8192;           // [128][64]
    unsigned short* sH  = smem;                  // [128][136] repack (alias)

    const int tid = threadIdx.x;
    const int lane = tid & 63;
    const int wave = tid >> 6;
    const int wy = wave >> 1, wx = wave & 1;
    const int lm = lane & 15, lq = lane >> 4;
    const int r8 = tid >> 3, ch = tid & 7;

    const int bid = blockIdx.x;
    const int e = bid % 5;
    const int nt = (bid / 5) & 3;
    const int rowtile = bid / 20;
    const int inst = z * 5 + e;

    const unsigned short* xp = xb + ((size_t)z * NB + rowtile * 128) * H;
    const unsigned short* wp = w1t + (size_t)inst * H * H + (size_t)(nt * 128) * H;
    const float* b1 = (z == 0) ? (share_b1 + e * H) : (task_b1 + ((z - 1) * 5 + e) * H);
    unsigned short* hp = hbuf + ((size_t)e * NB + rowtile * 128) * H + nt * 128;

    ushort8v rA[4], rB[4];
#pragma unroll
    for (int it = 0; it < 4; ++it) {
        rA[it] = *(const ushort8v*)&xp[(size_t)(it * 32 + r8) * H + ch * 8];
        rB[it] = *(const ushort8v*)&wp[(size_t)(it * 32 + r8) * H + ch * 8];
    }

    const f32x4 z4 = {0.f, 0.f, 0.f, 0.f};
    f32x4 acc[4][4];
#pragma unroll
    for (int i = 0; i < 4; ++i)
#pragma unroll
        for (int j = 0; j < 4; ++j) acc[i][j] = z4;

    for (int kt = 0; kt < 8; ++kt) {
        __syncthreads();
#pragma unroll
        for (int it = 0; it < 4; ++it) sw_write(sA, it * 32 + r8, ch, rA[it]);
#pragma unroll
        for (int it = 0; it < 4; ++it) sw_write(sBt, it * 32 + r8, ch, rB[it]);
        __syncthreads();
        if (kt < 7) {
            const int k0 = (kt + 1) * 64;
#pragma unroll
            for (int it = 0; it < 4; ++it) {
                rA[it] = *(const ushort8v*)&xp[(size_t)(it * 32 + r8) * H + k0 + ch * 8];
                rB[it] = *(const ushort8v*)&wp[(size_t)(it * 32 + r8) * H + k0 + ch * 8];
            }
        }
#pragma unroll
        for (int kk = 0; kk < 2; ++kk) {
            short8 af[4], bf[4];
#pragma unroll
            for (int i = 0; i < 4; ++i) af[i] = sw_read(sA, wy * 64 + i * 16 + lm, kk * 4 + lq);
#pragma unroll
            for (int j = 0; j < 4; ++j) bf[j] = sw_read(sBt, wx * 64 + j * 16 + lm, kk * 4 + lq);
#pragma unroll
            for (int i = 0; i < 4; ++i)
#pragma unroll
                for (int j = 0; j < 4; ++j) acc[i][j] = mfma16(af[i], bf[j], acc[i][j]);
        }
    }

    // epilogue: +b1, relu, bf16 -> sH repack -> coalesced b128 store
    __syncthreads();
#pragma unroll
    for (int j = 0; j < 4; ++j) {
        const int col = wx * 64 + j * 16 + lm;
        const float b1v = b1[nt * 128 + col];
#pragma unroll
        for (int i = 0; i < 4; ++i)
#pragma unroll
            for (int r = 0; r < 4; ++r) {
                const int row = wy * 64 + i * 16 + lq * 4 + r;
                sH[row * 136 + col] = f2bf(fmaxf(acc[i][j][r] + b1v, 0.f));
            }
    }
    __syncthreads();
    {
        const int rr = tid >> 4, cc = tid & 15;
#pragma unroll
        for (int it = 0; it < 8; ++it) {
            const int row = rr + it * 16;
            ushort8v v = *(const ushort8v*)&sH[row * 136 + cc * 8];
            *(ushort8v*)&hp[(size_t)row * H + cc * 8] = v;
        }
    }
}

// ---- GEMM2: out = h @ W2 + b2, fp32. grid 1280: bid = e + 5*rt. 64x128, K=512 ----
__global__ __launch_bounds__(256, 4) void gemm2(
    const unsigned short* __restrict__ hbuf, const unsigned short* __restrict__ w2t,
    const float* __restrict__ share_b2, const float* __restrict__ task_b2,
    float* __restrict__ out, int z)
{
    __shared__ unsigned short smem[4096 + 8192];   // sH 64x64, sW2 128x64 = 24 KB
    unsigned short* sH  = smem;
    unsigned short* sW2 = smem + 4096;

    const int tid = threadIdx.x;
    const int lane = tid & 63;
    const int wave = tid >> 6;
    const int wy = wave >> 1, wx = wave & 1;
    const int lm = lane & 15, lq = lane >> 4;
    const int r8 = tid >> 3, ch = tid & 7;

    const int bid = blockIdx.x;
    const int e = bid % 5;
    const int rt = bid / 5;                       // 0..255
    const int inst = z * 5 + e;

    const unsigned short* hp = hbuf + ((size_t)e * NB + rt * 64) * H;
    const unsigned short* wp = w2t + (size_t)inst * OW * H;
    const float* b2 = (z == 0) ? (share_b2 + e * OW) : (task_b2 + ((z - 1) * 5 + e) * OW);
    float* op = out + ((size_t)inst * NB + rt * 64) * OW;

    ushort8v rH[2], rW[4];
#pragma unroll
    for (int it = 0; it < 2; ++it)
        rH[it] = *(const ushort8v*)&hp[(size_t)(it * 32 + r8) * H + ch * 8];
#pragma unroll
    for (int it = 0; it < 4; ++it)
        rW[it] = *(const ushort8v*)&wp[(size_t)(it * 32 + r8) * H + ch * 8];

    const f32x4 z4 = {0.f, 0.f, 0.f, 0.f};
    f32x4 acc[2][4];
#pragma unroll
    for (int i = 0; i < 2; ++i)
#pragma unroll
        for (int j = 0; j < 4; ++j) acc[i][j] = z4;

    for (int kt = 0; kt < 8; ++kt) {
        __syncthreads();
#pragma unroll
        for (int it = 0; it < 2; ++it) sw_write(sH, it * 32 + r8, ch, rH[it]);
#pragma unroll
        for (int it = 0; it < 4; ++it) sw_write(sW2, it * 32 + r8, ch, rW[it]);
        __syncthreads();
        if (kt < 7) {
            const int k0 = (kt + 1) * 64;
#pragma unroll
            for (int it = 0; it < 2; ++it)
                rH[it] = *(const ushort8v*)&hp[(size_t)(it * 32 + r8) * H + k0 + ch * 8];
#pragma unroll
            for (int it = 0; it < 4; ++it)
                rW[it] = *(const ushort8v*)&wp[(size_t)(it * 32 + r8) * H + k0 + ch * 8];
        }
#pragma unroll
        for (int kk = 0; kk < 2; ++kk) {
            short8 af[2], bf[4];
#pragma unroll
            for (int i = 0; i < 2; ++i) af[i] = sw_read(sH, wy * 32 + i * 16 + lm, kk * 4 + lq);
#pragma unroll
            for (int j = 0; j < 4; ++j) bf[j] = sw_read(sW2, wx * 64 + j * 16 + lm, kk * 4 + lq);
#pragma unroll
            for (int i = 0; i < 2; ++i)
#pragma unroll
                for (int j = 0; j < 4; ++j) acc[i][j] = mfma16(af[i], bf[j], acc[i][j]);
        }
    }

#pragma unroll
    for (int j = 0; j < 4; ++j) {
        const int col = wx * 64 + j * 16 + lm;
        const float b2v = b2[col];
#pragma unroll
        for (int i = 0; i < 2; ++i)
#pragma unroll
            for (int r = 0; r < 4; ++r) {
                const int row = wy * 32 + i * 16 + lq * 4 + r;
                op[(size_t)row * OW + col] = acc[i][j][r] + b2v;
            }
    }
}

extern "C" void kernel_launch(void* const* d_in, const int* in_sizes, int n_in,
                              void* d_out, int out_size, void* d_ws, size_t ws_size,
                              hipStream_t stream) {
    const float* share_x  = (const float*)d_in[0];
    const float* task_x0  = (const float*)d_in[1];
    const float* task_x1  = (const float*)d_in[2];
    const float* share_W1 = (const float*)d_in[3];
    const float* share_b1 = (const float*)d_in[4];
    const float* share_W2 = (const float*)d_in[5];
    const float* share_b2 = (const float*)d_in[6];
    const float* task_W1  = (const float*)d_in[7];
    const float* task_b1  = (const float*)d_in[8];
    const float* task_W2  = (const float*)d_in[9];
    const float* task_b2  = (const float*)d_in[10];
    float* out = (float*)d_out;

    // ws layout (144.0 MB total): w1t 7.86M | w2t 1.97M | xb 50.3M | hbuf 83.9M
    unsigned short* w1t  = (unsigned short*)d_ws;
    unsigned short* w2t  = w1t + (size_t)15 * H * H;
    unsigned short* xb   = w2t + (size_t)15 * OW * H;
    unsigned short* hbuf = xb + (size_t)3 * NB * H;

    prep_w1<<<dim3(128, 1, 15), 256, 0, stream>>>(share_W1, task_W1, w1t);
    prep_w2<<<dim3(32, 1, 15), 256, 0, stream>>>(share_W2, task_W2, w2t);
    prep_x <<<dim3(4096, 1, 3), 256, 0, stream>>>(share_x, task_x0, task_x1, xb);
    for (int z = 0; z < 3; ++z) {
        gemm1<<<2560, 256, 0, stream>>>(xb, w1t, share_b1, task_b1, hbuf, z);
        gemm2<<<1280, 256, 0, stream>>>(hbuf, w2t, share_b2, task_b2, out, z);
    }
}